// Round 1
// baseline (1880.042 us; speedup 1.0000x reference)
//
#include <hip/hip_runtime.h>
#include <cstddef>

#define USER_COUNT_C 100000
#define ITEM_COUNT_C 100000
#define DIM_C 64
#define B_C 1024
#define NPOS_C 10
#define NTOP_C 50
#define CLAMP_C 40.0f
#define EPS_C 1e-5f

// ---- main expsum kernel tiling ----
#define ROWS 64              // rows per block
#define TI 64                // items per LDS tile
#define IT_STRIDE 68         // pad: keeps b128 16B-aligned, 2-way (free) bank pattern
#define NTILES ((ITEM_COUNT_C + TI - 1) / TI)   // 1563
#define ITEM_BLOCKS 128      // grid.x; each block strides over tiles

__global__ void zero_ws_kernel(float* __restrict__ ws) {
    ws[threadIdx.x] = 0.0f;  // launched with B_C threads
}

// exp_sum[b] = sum_i exp(clip(u_b . item_i, +-40)) * (1 - mask[b][i])
__global__ __launch_bounds__(256) void expsum_kernel(
    const float* __restrict__ user_emb,
    const float* __restrict__ item_emb,
    const int*   __restrict__ batch_user,
    const float* __restrict__ mask,
    float*       __restrict__ exp_sum)
{
    __shared__ float u_t[DIM_C * ROWS];      // [d][r] transposed user tile
    __shared__ float it[TI * IT_STRIDE];     // [item][d] natural, padded
    __shared__ int   uidx[ROWS];

    const int tid = threadIdx.x;
    const int rowBase = blockIdx.y * ROWS;

    if (tid < ROWS) uidx[tid] = batch_user[rowBase + tid];
    __syncthreads();

    // stage u transposed: thread t -> row t>>2, dim-quarter t&3
    {
        const int r = tid >> 2;
        const int f = tid & 3;
        const float* src = user_emb + (size_t)uidx[r] * DIM_C + f * 16;
        #pragma unroll
        for (int jj = 0; jj < 4; ++jj) {
            float4 v = *(const float4*)(src + jj * 4);
            const int d = f * 16 + jj * 4;
            u_t[(d + 0) * ROWS + r] = v.x;
            u_t[(d + 1) * ROWS + r] = v.y;
            u_t[(d + 2) * ROWS + r] = v.z;
            u_t[(d + 3) * ROWS + r] = v.w;
        }
    }

    const int itemIdx = tid & 15;   // 0..15 -> items itemIdx + 16k
    const int rowIdx  = tid >> 4;   // 0..15 -> rows rowIdx*4 + rr
    float accExp[4] = {0.f, 0.f, 0.f, 0.f};

    for (int t = blockIdx.x; t < NTILES; t += ITEM_BLOCKS) {
        const int ibase = t * TI;
        __syncthreads();  // protect it[] reuse (also covers u_t visibility on 1st iter)

        // stage item tile, coalesced float4 reads, b128 LDS writes
        #pragma unroll
        for (int p = 0; p < 4; ++p) {
            const int q = tid + 256 * p;
            const int itm = q >> 4;
            const int d4  = (q & 15) * 4;
            const int gi  = ibase + itm;
            float4 v = make_float4(0.f, 0.f, 0.f, 0.f);
            if (gi < ITEM_COUNT_C)
                v = *(const float4*)(item_emb + (size_t)gi * DIM_C + d4);
            *(float4*)&it[itm * IT_STRIDE + d4] = v;
        }
        __syncthreads();

        float acc[4][4];
        #pragma unroll
        for (int rr = 0; rr < 4; ++rr)
            #pragma unroll
            for (int k = 0; k < 4; ++k) acc[rr][k] = 0.f;

        #pragma unroll
        for (int d4 = 0; d4 < 16; ++d4) {
            float4 bv[4];
            #pragma unroll
            for (int k = 0; k < 4; ++k)
                bv[k] = *(const float4*)&it[(itemIdx + 16 * k) * IT_STRIDE + d4 * 4];
            #pragma unroll
            for (int j = 0; j < 4; ++j) {
                const float4 uv = *(const float4*)&u_t[(d4 * 4 + j) * ROWS + rowIdx * 4];
                #pragma unroll
                for (int k = 0; k < 4; ++k) {
                    const float bb = ((const float*)&bv[k])[j];
                    acc[0][k] += uv.x * bb;
                    acc[1][k] += uv.y * bb;
                    acc[2][k] += uv.z * bb;
                    acc[3][k] += uv.w * bb;
                }
            }
        }

        // epilogue: clip -> exp -> mask weight -> per-row accumulate
        #pragma unroll
        for (int k = 0; k < 4; ++k) {
            const int gi = ibase + itemIdx + 16 * k;
            const bool valid = (gi < ITEM_COUNT_C);
            #pragma unroll
            for (int rr = 0; rr < 4; ++rr) {
                const int b = rowBase + rowIdx * 4 + rr;
                const float s = fminf(fmaxf(acc[rr][k], -CLAMP_C), CLAMP_C);
                const float e = __expf(s);
                float w = 0.f;
                if (valid) w = 1.0f - mask[(size_t)b * ITEM_COUNT_C + gi];
                accExp[rr] += e * w;
            }
        }
    }

    // reduce across the 16 lanes sharing a row (lanes differ only in itemIdx bits 0..3)
    #pragma unroll
    for (int off = 1; off < 16; off <<= 1) {
        #pragma unroll
        for (int rr = 0; rr < 4; ++rr)
            accExp[rr] += __shfl_xor(accExp[rr], off, 64);
    }
    if (itemIdx == 0) {
        #pragma unroll
        for (int rr = 0; rr < 4; ++rr)
            atomicAdd(&exp_sum[rowBase + rowIdx * 4 + rr], accExp[rr]);
    }
}

// per-row: 60 sampled scores + loss math -> row_loss[b]
__global__ void finalize_kernel(
    const float* __restrict__ user_emb,
    const float* __restrict__ item_emb,
    const int*   __restrict__ batch_user,
    const int*   __restrict__ pos_items,
    const int*   __restrict__ top_items,
    const float* __restrict__ exp_sum,
    const int*   __restrict__ is_final,
    float*       __restrict__ row_loss)
{
    __shared__ float ush[DIM_C];
    __shared__ float s_sh[NPOS_C + NTOP_C];
    const int b = blockIdx.x;
    const int tid = threadIdx.x;  // 64 threads
    const int uidx = batch_user[b];
    if (tid < 16)
        *(float4*)&ush[tid * 4] = *(const float4*)(user_emb + (size_t)uidx * DIM_C + tid * 4);
    __syncthreads();

    if (tid < NPOS_C + NTOP_C) {
        const int idx = (tid < NPOS_C) ? pos_items[b * NPOS_C + tid]
                                       : top_items[b * NTOP_C + (tid - NPOS_C)];
        const float* iv = item_emb + (size_t)idx * DIM_C;
        float s = 0.f;
        #pragma unroll
        for (int d4 = 0; d4 < 16; ++d4) {
            const float4 a = *(const float4*)(iv + d4 * 4);
            s += a.x * ush[d4 * 4 + 0] + a.y * ush[d4 * 4 + 1]
               + a.z * ush[d4 * 4 + 2] + a.w * ush[d4 * 4 + 3];
        }
        s_sh[tid] = fminf(fmaxf(s, -CLAMP_C), CLAMP_C);
    }
    __syncthreads();

    if (tid == 0) {
        const float E = exp_sum[b];
        float L;
        if (is_final[0] != 0) {
            // ---- rank loss ----
            float sumExpTop = 0.f, above_top = 0.f;
            for (int i = 0; i < NTOP_C / 2; ++i) {
                const float v = s_sh[NPOS_C + i];
                sumExpTop += __expf(v); above_top += v;
            }
            const float below2 = E - sumExpTop;
            float above_pos = 0.f;
            for (int i = 0; i < NPOS_C; ++i) above_pos += s_sh[i];
            float c = 0.f, below_pos = 0.f;
            for (int i = 0; i < NPOS_C; ++i) {
                c += __expf(s_sh[NPOS_C - 1 - i]);
                below_pos += __logf(fmaxf(c + below2, EPS_C));
            }
            float c2 = 0.f, below_top = 0.f;
            for (int i = 0; i < NTOP_C / 2; ++i) {
                c2 += __expf(s_sh[NPOS_C + NTOP_C / 2 - 1 - i]);
                below_top += __logf(fmaxf(c2 + below2, EPS_C));
            }
            const float pos_KD = below_pos - above_pos;
            float sumExpSub = 0.f, above_sub = 0.f;
            for (int i = 0; i < NTOP_C / 10; ++i) {
                const float v = s_sh[NPOS_C + i];
                sumExpSub += __expf(v); above_sub += v;
            }
            const float below2s = E - sumExpSub;
            float c3 = 0.f, below_sub = 0.f;
            for (int i = 0; i < NTOP_C / 10; ++i) {
                c3 += __expf(s_sh[NPOS_C + NTOP_C / 10 - 1 - i]);
                below_sub += __logf(fmaxf(c3 + below2s, EPS_C));
            }
            const float top_KD = (below_top - above_top) + (below_sub - above_sub);
            L = pos_KD + 0.5f * top_KD;
        } else {
            // ---- overall loss ----
            float sumExpTop = 0.f;
            for (int i = 0; i < NTOP_C; ++i) sumExpTop += __expf(s_sh[NPOS_C + i]);
            const float els = E - sumExpTop;
            L = 0.f;
            for (int j = 0; j < NPOS_C + NTOP_C; ++j) {
                const float a = s_sh[j];
                L += __logf(fmaxf(els + __expf(a), EPS_C)) - a;
            }
        }
        row_loss[b] = L;
    }
}

__global__ void reduce_kernel(const float* __restrict__ rl, float* __restrict__ out) {
    __shared__ float part[16];
    const int tid = threadIdx.x;  // 1024 threads = 16 waves
    float v = rl[tid];
    #pragma unroll
    for (int off = 32; off > 0; off >>= 1) v += __shfl_down(v, off, 64);
    if ((tid & 63) == 0) part[tid >> 6] = v;
    __syncthreads();
    if (tid == 0) {
        float s = 0.f;
        #pragma unroll
        for (int i = 0; i < 16; ++i) s += part[i];
        out[0] = s;
    }
}

extern "C" void kernel_launch(void* const* d_in, const int* in_sizes, int n_in,
                              void* d_out, int out_size, void* d_ws, size_t ws_size,
                              hipStream_t stream) {
    const float* user_emb   = (const float*)d_in[0];
    const float* item_emb   = (const float*)d_in[1];
    const int*   batch_user = (const int*)d_in[2];
    const int*   pos_items  = (const int*)d_in[3];
    const int*   top_items  = (const int*)d_in[4];
    const float* mask       = (const float*)d_in[5];
    const int*   is_final   = (const int*)d_in[6];
    float* out = (float*)d_out;

    float* exp_sum  = (float*)d_ws;       // [B_C]
    float* row_loss = exp_sum + B_C;      // [B_C]

    hipLaunchKernelGGL(zero_ws_kernel, dim3(1), dim3(B_C), 0, stream, exp_sum);
    hipLaunchKernelGGL(expsum_kernel, dim3(ITEM_BLOCKS, B_C / ROWS), dim3(256), 0, stream,
                       user_emb, item_emb, batch_user, mask, exp_sum);
    hipLaunchKernelGGL(finalize_kernel, dim3(B_C), dim3(64), 0, stream,
                       user_emb, item_emb, batch_user, pos_items, top_items,
                       exp_sum, is_final, row_loss);
    hipLaunchKernelGGL(reduce_kernel, dim3(1), dim3(B_C), 0, stream, row_loss, out);
}

// Round 2
// 797.145 us; speedup vs baseline: 2.3585x; 2.3585x over previous
//
#include <hip/hip_runtime.h>
#include <cstddef>
#include <cstdint>

#define USER_COUNT_C 100000
#define ITEM_COUNT_C 100000
#define DIM_C 64
#define B_C 1024
#define NPOS_C 10
#define NTOP_C 50
#define CLAMP_C 40.0f
#define EPS_C 1e-5f

#define TI 64                                   // items per tile
#define NTILES ((ITEM_COUNT_C + TI - 1) / TI)   // 1563
#define ITEM_BLOCKS 64                          // grid.x

using bf16x8 = __attribute__((ext_vector_type(8))) short;
using f32x4  = __attribute__((ext_vector_type(4))) float;

__global__ void zero_ws_kernel(float* __restrict__ ws) {
    ws[threadIdx.x] = 0.0f;  // B_C threads
}

// RNE fp32 -> bf16 bits
__device__ inline short f2bf(float x) {
    uint32_t b = __float_as_uint(x);
    uint32_t r = (b + 0x7fffu + ((b >> 16) & 1u)) >> 16;
    return (short)r;
}

// load 8 consecutive floats at p, convert to a bf16x8 fragment
__device__ inline bf16x8 cvt8(const float* __restrict__ p) {
    float4 v0 = *(const float4*)p;
    float4 v1 = *(const float4*)(p + 4);
    bf16x8 r;
    r[0] = f2bf(v0.x); r[1] = f2bf(v0.y); r[2] = f2bf(v0.z); r[3] = f2bf(v0.w);
    r[4] = f2bf(v1.x); r[5] = f2bf(v1.y); r[6] = f2bf(v1.z); r[7] = f2bf(v1.w);
    return r;
}

// exp_sum[b] = sum_i exp(clip(u_b . item_i, +-40)) * (1 - mask[b][i])
// MFMA 16x16x32 bf16. Block = 4 waves; wave w owns users blockIdx.y*64 + w*16 .. +15.
// No LDS. A-frags in registers for whole kernel; B-frags converted on the fly.
__global__ __launch_bounds__(256) void expsum_mfma_kernel(
    const float* __restrict__ user_emb,
    const float* __restrict__ item_emb,
    const int*   __restrict__ batch_user,
    const float* __restrict__ mask,
    float*       __restrict__ exp_sum)
{
    const int tid  = threadIdx.x;
    const int wave = tid >> 6;
    const int lane = tid & 63;
    const int n16  = lane & 15;   // A: m-index / B: n-index / C: col
    const int quad = lane >> 4;   // frag k-group; C: row-group
    const int rowBase = blockIdx.y * 64 + wave * 16;

    // A fragments: user row rowBase+n16, k halves [0,32) and [32,64)
    const int uidx = batch_user[rowBase + n16];
    const float* usrc = user_emb + (size_t)uidx * DIM_C + quad * 8;
    const bf16x8 a0 = cvt8(usrc);        // k = quad*8 + j
    const bf16x8 a1 = cvt8(usrc + 32);   // k = 32 + quad*8 + j

    float accExp[4] = {0.f, 0.f, 0.f, 0.f};

    for (int t = blockIdx.x; t < NTILES; t += ITEM_BLOCKS) {
        const int ibase = t * TI;

        // B fragments for 4 sub-tiles of 16 items x (k halves)
        bf16x8 b0[4], b1[4];
        int   gic[4];
        bool  valid[4];
        #pragma unroll
        for (int s = 0; s < 4; ++s) {
            const int gi = ibase + s * 16 + n16;
            valid[s] = (gi < ITEM_COUNT_C);
            gic[s]   = valid[s] ? gi : (ITEM_COUNT_C - 1);
            const float* isrc = item_emb + (size_t)gic[s] * DIM_C + quad * 8;
            b0[s] = cvt8(isrc);
            b1[s] = cvt8(isrc + 32);
        }

        f32x4 acc[4];
        #pragma unroll
        for (int s = 0; s < 4; ++s) {
            acc[s] = (f32x4){0.f, 0.f, 0.f, 0.f};
            acc[s] = __builtin_amdgcn_mfma_f32_16x16x32_bf16(a0, b0[s], acc[s], 0, 0, 0);
            acc[s] = __builtin_amdgcn_mfma_f32_16x16x32_bf16(a1, b1[s], acc[s], 0, 0, 0);
        }

        // epilogue: clamp -> exp -> (1-mask) weight -> accumulate per C-row
        #pragma unroll
        for (int s = 0; s < 4; ++s) {
            #pragma unroll
            for (int reg = 0; reg < 4; ++reg) {
                const int row = rowBase + quad * 4 + reg;   // C row = quad*4+reg
                const float sc = fminf(fmaxf(acc[s][reg], -CLAMP_C), CLAMP_C);
                const float e  = __expf(sc);
                float w = 0.f;
                if (valid[s]) {
                    const float m = __builtin_nontemporal_load(
                        mask + (size_t)row * ITEM_COUNT_C + gic[s]);
                    w = 1.0f - m;
                }
                accExp[reg] += e * w;
            }
        }
    }

    // reduce over the 16 lanes of each quad (they hold different items, same rows)
    #pragma unroll
    for (int off = 1; off < 16; off <<= 1) {
        #pragma unroll
        for (int reg = 0; reg < 4; ++reg)
            accExp[reg] += __shfl_xor(accExp[reg], off, 64);
    }
    if (n16 == 0) {
        #pragma unroll
        for (int reg = 0; reg < 4; ++reg)
            atomicAdd(&exp_sum[rowBase + quad * 4 + reg], accExp[reg]);
    }
}

// per-row: 60 sampled scores (exact fp32) + loss math -> row_loss[b]
__global__ void finalize_kernel(
    const float* __restrict__ user_emb,
    const float* __restrict__ item_emb,
    const int*   __restrict__ batch_user,
    const int*   __restrict__ pos_items,
    const int*   __restrict__ top_items,
    const float* __restrict__ exp_sum,
    const int*   __restrict__ is_final,
    float*       __restrict__ row_loss)
{
    __shared__ float ush[DIM_C];
    __shared__ float s_sh[NPOS_C + NTOP_C];
    const int b = blockIdx.x;
    const int tid = threadIdx.x;  // 64 threads
    const int uidx = batch_user[b];
    if (tid < 16)
        *(float4*)&ush[tid * 4] = *(const float4*)(user_emb + (size_t)uidx * DIM_C + tid * 4);
    __syncthreads();

    if (tid < NPOS_C + NTOP_C) {
        const int idx = (tid < NPOS_C) ? pos_items[b * NPOS_C + tid]
                                       : top_items[b * NTOP_C + (tid - NPOS_C)];
        const float* iv = item_emb + (size_t)idx * DIM_C;
        float s = 0.f;
        #pragma unroll
        for (int d4 = 0; d4 < 16; ++d4) {
            const float4 a = *(const float4*)(iv + d4 * 4);
            s += a.x * ush[d4 * 4 + 0] + a.y * ush[d4 * 4 + 1]
               + a.z * ush[d4 * 4 + 2] + a.w * ush[d4 * 4 + 3];
        }
        s_sh[tid] = fminf(fmaxf(s, -CLAMP_C), CLAMP_C);
    }
    __syncthreads();

    if (tid == 0) {
        const float E = exp_sum[b];
        float L;
        if (is_final[0] != 0) {
            float sumExpTop = 0.f, above_top = 0.f;
            for (int i = 0; i < NTOP_C / 2; ++i) {
                const float v = s_sh[NPOS_C + i];
                sumExpTop += __expf(v); above_top += v;
            }
            const float below2 = E - sumExpTop;
            float above_pos = 0.f;
            for (int i = 0; i < NPOS_C; ++i) above_pos += s_sh[i];
            float c = 0.f, below_pos = 0.f;
            for (int i = 0; i < NPOS_C; ++i) {
                c += __expf(s_sh[NPOS_C - 1 - i]);
                below_pos += __logf(fmaxf(c + below2, EPS_C));
            }
            float c2 = 0.f, below_top = 0.f;
            for (int i = 0; i < NTOP_C / 2; ++i) {
                c2 += __expf(s_sh[NPOS_C + NTOP_C / 2 - 1 - i]);
                below_top += __logf(fmaxf(c2 + below2, EPS_C));
            }
            const float pos_KD = below_pos - above_pos;
            float sumExpSub = 0.f, above_sub = 0.f;
            for (int i = 0; i < NTOP_C / 10; ++i) {
                const float v = s_sh[NPOS_C + i];
                sumExpSub += __expf(v); above_sub += v;
            }
            const float below2s = E - sumExpSub;
            float c3 = 0.f, below_sub = 0.f;
            for (int i = 0; i < NTOP_C / 10; ++i) {
                c3 += __expf(s_sh[NPOS_C + NTOP_C / 10 - 1 - i]);
                below_sub += __logf(fmaxf(c3 + below2s, EPS_C));
            }
            const float top_KD = (below_top - above_top) + (below_sub - above_sub);
            L = pos_KD + 0.5f * top_KD;
        } else {
            float sumExpTop = 0.f;
            for (int i = 0; i < NTOP_C; ++i) sumExpTop += __expf(s_sh[NPOS_C + i]);
            const float els = E - sumExpTop;
            L = 0.f;
            for (int j = 0; j < NPOS_C + NTOP_C; ++j) {
                const float a = s_sh[j];
                L += __logf(fmaxf(els + __expf(a), EPS_C)) - a;
            }
        }
        row_loss[b] = L;
    }
}

__global__ void reduce_kernel(const float* __restrict__ rl, float* __restrict__ out) {
    __shared__ float part[16];
    const int tid = threadIdx.x;  // 1024 threads = 16 waves
    float v = rl[tid];
    #pragma unroll
    for (int off = 32; off > 0; off >>= 1) v += __shfl_down(v, off, 64);
    if ((tid & 63) == 0) part[tid >> 6] = v;
    __syncthreads();
    if (tid == 0) {
        float s = 0.f;
        #pragma unroll
        for (int i = 0; i < 16; ++i) s += part[i];
        out[0] = s;
    }
}

extern "C" void kernel_launch(void* const* d_in, const int* in_sizes, int n_in,
                              void* d_out, int out_size, void* d_ws, size_t ws_size,
                              hipStream_t stream) {
    const float* user_emb   = (const float*)d_in[0];
    const float* item_emb   = (const float*)d_in[1];
    const int*   batch_user = (const int*)d_in[2];
    const int*   pos_items  = (const int*)d_in[3];
    const int*   top_items  = (const int*)d_in[4];
    const float* mask       = (const float*)d_in[5];
    const int*   is_final   = (const int*)d_in[6];
    float* out = (float*)d_out;

    float* exp_sum  = (float*)d_ws;       // [B_C]
    float* row_loss = exp_sum + B_C;      // [B_C]

    hipLaunchKernelGGL(zero_ws_kernel, dim3(1), dim3(B_C), 0, stream, exp_sum);
    hipLaunchKernelGGL(expsum_mfma_kernel, dim3(ITEM_BLOCKS, B_C / 64), dim3(256), 0, stream,
                       user_emb, item_emb, batch_user, mask, exp_sum);
    hipLaunchKernelGGL(finalize_kernel, dim3(B_C), dim3(64), 0, stream,
                       user_emb, item_emb, batch_user, pos_items, top_items,
                       exp_sum, is_final, row_loss);
    hipLaunchKernelGGL(reduce_kernel, dim3(1), dim3(B_C), 0, stream, row_loss, out);
}

// Round 3
// 609.001 us; speedup vs baseline: 3.0871x; 1.3089x over previous
//
#include <hip/hip_runtime.h>
#include <cstddef>
#include <cstdint>

#define USER_COUNT_C 100000
#define ITEM_COUNT_C 100000
#define DIM_C 64
#define B_C 1024
#define NPOS_C 10
#define NTOP_C 50
#define CLAMP_C 40.0f
#define EPS_C 1e-5f

#define TI 64                                   // items per tile
#define NTILES ((ITEM_COUNT_C + TI - 1) / TI)   // 1563 (last tile: 32 items)
#define ITEM_BLOCKS 64                          // grid.x
#define NGROUPS 6250                            // 100000/16 item groups of 16
#define NGROUPS_PAD 6252                        // padded to tile boundary (1563*4)

using bf16x8 = __attribute__((ext_vector_type(8))) short;
using f32x4  = __attribute__((ext_vector_type(4))) float;

__global__ void zero_ws_kernel(float* __restrict__ ws) {
    ws[threadIdx.x] = 0.0f;  // B_C threads
}

// RNE fp32 -> bf16 bits
__device__ inline short f2bf(float x) {
    uint32_t b = __float_as_uint(x);
    uint32_t r = (b + 0x7fffu + ((b >> 16) & 1u)) >> 16;
    return (short)r;
}

__device__ inline bf16x8 cvt8(const float* __restrict__ p) {
    float4 v0 = *(const float4*)p;
    float4 v1 = *(const float4*)(p + 4);
    bf16x8 r;
    r[0] = f2bf(v0.x); r[1] = f2bf(v0.y); r[2] = f2bf(v0.z); r[3] = f2bf(v0.w);
    r[4] = f2bf(v1.x); r[5] = f2bf(v1.y); r[6] = f2bf(v1.z); r[7] = f2bf(v1.w);
    return r;
}

// item_bf16 layout: frag-ready. For group g (16 items), half h (k 0/1),
// quad q, item-in-group n16: 8 bf16 at ((g*2+h)*4+q)*128 + n16*8.
// Main kernel's B-frag load is then a fully-contiguous 1KB dwordx4 per wave.
__global__ __launch_bounds__(256) void prep_items_kernel(
    const float* __restrict__ item_emb, short* __restrict__ item_bf16) {
    const int t = blockIdx.x * 256 + threadIdx.x;   // NGROUPS_PAD*128 total
    const int n16 = t & 15;
    const int q   = (t >> 4) & 3;
    const int h   = (t >> 6) & 1;
    const int g   = t >> 7;
    const int i   = g * 16 + n16;
    bf16x8 v;
    if (i < ITEM_COUNT_C) {
        v = cvt8(item_emb + (size_t)i * DIM_C + h * 32 + q * 8);
    } else {
        #pragma unroll
        for (int j = 0; j < 8; ++j) v[j] = 0;
    }
    *(bf16x8*)(item_bf16 + (((size_t)g * 2 + h) * 4 + q) * 128 + n16 * 8) = v;
}

// exp_sum[b] = sum_i exp(clip(u_b . item_i, +-40)) * (1 - mask[b][i])
// MFMA 16x16x32 bf16; wave owns 16 users; no LDS; bf16 items loaded frag-ready;
// mask loads software-pipelined one tile ahead (batched -> high MLP).
__global__ __launch_bounds__(256, 4) void expsum_mfma2_kernel(
    const float* __restrict__ user_emb,
    const short* __restrict__ item_bf16,
    const int*   __restrict__ batch_user,
    const float* __restrict__ mask,
    float*       __restrict__ exp_sum)
{
    const int tid  = threadIdx.x;
    const int wave = tid >> 6;
    const int lane = tid & 63;
    const int n16  = lane & 15;
    const int quad = lane >> 4;
    const int rowBase = blockIdx.y * 64 + wave * 16;

    // A fragments (users), gathered + converted once
    const int uidx = batch_user[rowBase + n16];
    const float* usrc = user_emb + (size_t)uidx * DIM_C + quad * 8;
    const bf16x8 a0 = cvt8(usrc);
    const bf16x8 a1 = cvt8(usrc + 32);

    float accExp[4] = {0.f, 0.f, 0.f, 0.f};

    // batched mask loads for tile tt -> dst[16]
    const float* mbase = mask + (size_t)(rowBase + quad * 4) * ITEM_COUNT_C;
    auto load_masks = [&](int tt, float* dst) {
        const int ibase = tt * TI;
        #pragma unroll
        for (int s = 0; s < 4; ++s) {
            int gi = ibase + s * 16 + n16;
            gi = gi < ITEM_COUNT_C ? gi : ITEM_COUNT_C - 1;
            #pragma unroll
            for (int r = 0; r < 4; ++r)
                dst[s * 4 + r] = __builtin_nontemporal_load(
                    mbase + (size_t)r * ITEM_COUNT_C + gi);
        }
    };

    float mcur[16];
    load_masks(blockIdx.x, mcur);

    for (int t = blockIdx.x; t < NTILES; t += ITEM_BLOCKS) {
        // 1. prefetch next tile's masks (consumed next iteration)
        float mnext[16];
        const int tn = t + ITEM_BLOCKS;
        load_masks(tn < NTILES ? tn : blockIdx.x, mnext);

        // 2. B fragments, frag-ready bf16, contiguous 1KB per instr
        bf16x8 b0[4], b1[4];
        #pragma unroll
        for (int s = 0; s < 4; ++s) {
            const size_t g = (size_t)(t * 4 + s);
            b0[s] = *(const bf16x8*)(item_bf16 + ((g * 2 + 0) * 4 + quad) * 128 + n16 * 8);
            b1[s] = *(const bf16x8*)(item_bf16 + ((g * 2 + 1) * 4 + quad) * 128 + n16 * 8);
        }

        // 3. MFMA
        f32x4 acc[4];
        #pragma unroll
        for (int s = 0; s < 4; ++s) {
            acc[s] = (f32x4){0.f, 0.f, 0.f, 0.f};
            acc[s] = __builtin_amdgcn_mfma_f32_16x16x32_bf16(a0, b0[s], acc[s], 0, 0, 0);
            acc[s] = __builtin_amdgcn_mfma_f32_16x16x32_bf16(a1, b1[s], acc[s], 0, 0, 0);
        }

        // 4. epilogue with current masks (already in registers)
        const int ibase = t * TI;
        #pragma unroll
        for (int s = 0; s < 4; ++s) {
            const bool valid = (ibase + s * 16 + n16) < ITEM_COUNT_C;
            #pragma unroll
            for (int reg = 0; reg < 4; ++reg) {
                const float sc = fminf(fmaxf(acc[s][reg], -CLAMP_C), CLAMP_C);
                const float e  = __expf(sc);
                const float w  = valid ? (1.0f - mcur[s * 4 + reg]) : 0.0f;
                accExp[reg] += e * w;
            }
        }

        #pragma unroll
        for (int i = 0; i < 16; ++i) mcur[i] = mnext[i];
    }

    #pragma unroll
    for (int off = 1; off < 16; off <<= 1) {
        #pragma unroll
        for (int reg = 0; reg < 4; ++reg)
            accExp[reg] += __shfl_xor(accExp[reg], off, 64);
    }
    if (n16 == 0) {
        #pragma unroll
        for (int reg = 0; reg < 4; ++reg)
            atomicAdd(&exp_sum[rowBase + quad * 4 + reg], accExp[reg]);
    }
}

// Fallback (ws too small for bf16 item buffer): R2 kernel, fp32 items from global
__global__ __launch_bounds__(256) void expsum_fallback_kernel(
    const float* __restrict__ user_emb,
    const float* __restrict__ item_emb,
    const int*   __restrict__ batch_user,
    const float* __restrict__ mask,
    float*       __restrict__ exp_sum)
{
    const int tid  = threadIdx.x;
    const int wave = tid >> 6;
    const int lane = tid & 63;
    const int n16  = lane & 15;
    const int quad = lane >> 4;
    const int rowBase = blockIdx.y * 64 + wave * 16;

    const int uidx = batch_user[rowBase + n16];
    const float* usrc = user_emb + (size_t)uidx * DIM_C + quad * 8;
    const bf16x8 a0 = cvt8(usrc);
    const bf16x8 a1 = cvt8(usrc + 32);

    float accExp[4] = {0.f, 0.f, 0.f, 0.f};

    for (int t = blockIdx.x; t < NTILES; t += ITEM_BLOCKS) {
        const int ibase = t * TI;
        bf16x8 b0[4], b1[4];
        int gic[4]; bool valid[4];
        #pragma unroll
        for (int s = 0; s < 4; ++s) {
            const int gi = ibase + s * 16 + n16;
            valid[s] = (gi < ITEM_COUNT_C);
            gic[s]   = valid[s] ? gi : (ITEM_COUNT_C - 1);
            const float* isrc = item_emb + (size_t)gic[s] * DIM_C + quad * 8;
            b0[s] = cvt8(isrc);
            b1[s] = cvt8(isrc + 32);
        }
        f32x4 acc[4];
        #pragma unroll
        for (int s = 0; s < 4; ++s) {
            acc[s] = (f32x4){0.f, 0.f, 0.f, 0.f};
            acc[s] = __builtin_amdgcn_mfma_f32_16x16x32_bf16(a0, b0[s], acc[s], 0, 0, 0);
            acc[s] = __builtin_amdgcn_mfma_f32_16x16x32_bf16(a1, b1[s], acc[s], 0, 0, 0);
        }
        #pragma unroll
        for (int s = 0; s < 4; ++s) {
            #pragma unroll
            for (int reg = 0; reg < 4; ++reg) {
                const int row = rowBase + quad * 4 + reg;
                const float sc = fminf(fmaxf(acc[s][reg], -CLAMP_C), CLAMP_C);
                const float e  = __expf(sc);
                float w = 0.f;
                if (valid[s])
                    w = 1.0f - __builtin_nontemporal_load(
                        mask + (size_t)row * ITEM_COUNT_C + gic[s]);
                accExp[reg] += e * w;
            }
        }
    }
    #pragma unroll
    for (int off = 1; off < 16; off <<= 1) {
        #pragma unroll
        for (int reg = 0; reg < 4; ++reg)
            accExp[reg] += __shfl_xor(accExp[reg], off, 64);
    }
    if (n16 == 0) {
        #pragma unroll
        for (int reg = 0; reg < 4; ++reg)
            atomicAdd(&exp_sum[rowBase + quad * 4 + reg], accExp[reg]);
    }
}

// per-row: 60 sampled scores (exact fp32) + loss math -> row_loss[b]
__global__ void finalize_kernel(
    const float* __restrict__ user_emb,
    const float* __restrict__ item_emb,
    const int*   __restrict__ batch_user,
    const int*   __restrict__ pos_items,
    const int*   __restrict__ top_items,
    const float* __restrict__ exp_sum,
    const int*   __restrict__ is_final,
    float*       __restrict__ row_loss)
{
    __shared__ float ush[DIM_C];
    __shared__ float s_sh[NPOS_C + NTOP_C];
    const int b = blockIdx.x;
    const int tid = threadIdx.x;  // 64 threads
    const int uidx = batch_user[b];
    if (tid < 16)
        *(float4*)&ush[tid * 4] = *(const float4*)(user_emb + (size_t)uidx * DIM_C + tid * 4);
    __syncthreads();

    if (tid < NPOS_C + NTOP_C) {
        const int idx = (tid < NPOS_C) ? pos_items[b * NPOS_C + tid]
                                       : top_items[b * NTOP_C + (tid - NPOS_C)];
        const float* iv = item_emb + (size_t)idx * DIM_C;
        float s = 0.f;
        #pragma unroll
        for (int d4 = 0; d4 < 16; ++d4) {
            const float4 a = *(const float4*)(iv + d4 * 4);
            s += a.x * ush[d4 * 4 + 0] + a.y * ush[d4 * 4 + 1]
               + a.z * ush[d4 * 4 + 2] + a.w * ush[d4 * 4 + 3];
        }
        s_sh[tid] = fminf(fmaxf(s, -CLAMP_C), CLAMP_C);
    }
    __syncthreads();

    if (tid == 0) {
        const float E = exp_sum[b];
        float L;
        if (is_final[0] != 0) {
            float sumExpTop = 0.f, above_top = 0.f;
            for (int i = 0; i < NTOP_C / 2; ++i) {
                const float v = s_sh[NPOS_C + i];
                sumExpTop += __expf(v); above_top += v;
            }
            const float below2 = E - sumExpTop;
            float above_pos = 0.f;
            for (int i = 0; i < NPOS_C; ++i) above_pos += s_sh[i];
            float c = 0.f, below_pos = 0.f;
            for (int i = 0; i < NPOS_C; ++i) {
                c += __expf(s_sh[NPOS_C - 1 - i]);
                below_pos += __logf(fmaxf(c + below2, EPS_C));
            }
            float c2 = 0.f, below_top = 0.f;
            for (int i = 0; i < NTOP_C / 2; ++i) {
                c2 += __expf(s_sh[NPOS_C + NTOP_C / 2 - 1 - i]);
                below_top += __logf(fmaxf(c2 + below2, EPS_C));
            }
            const float pos_KD = below_pos - above_pos;
            float sumExpSub = 0.f, above_sub = 0.f;
            for (int i = 0; i < NTOP_C / 10; ++i) {
                const float v = s_sh[NPOS_C + i];
                sumExpSub += __expf(v); above_sub += v;
            }
            const float below2s = E - sumExpSub;
            float c3 = 0.f, below_sub = 0.f;
            for (int i = 0; i < NTOP_C / 10; ++i) {
                c3 += __expf(s_sh[NPOS_C + NTOP_C / 10 - 1 - i]);
                below_sub += __logf(fmaxf(c3 + below2s, EPS_C));
            }
            const float top_KD = (below_top - above_top) + (below_sub - above_sub);
            L = pos_KD + 0.5f * top_KD;
        } else {
            float sumExpTop = 0.f;
            for (int i = 0; i < NTOP_C; ++i) sumExpTop += __expf(s_sh[NPOS_C + i]);
            const float els = E - sumExpTop;
            L = 0.f;
            for (int j = 0; j < NPOS_C + NTOP_C; ++j) {
                const float a = s_sh[j];
                L += __logf(fmaxf(els + __expf(a), EPS_C)) - a;
            }
        }
        row_loss[b] = L;
    }
}

__global__ void reduce_kernel(const float* __restrict__ rl, float* __restrict__ out) {
    __shared__ float part[16];
    const int tid = threadIdx.x;  // 1024 threads = 16 waves
    float v = rl[tid];
    #pragma unroll
    for (int off = 32; off > 0; off >>= 1) v += __shfl_down(v, off, 64);
    if ((tid & 63) == 0) part[tid >> 6] = v;
    __syncthreads();
    if (tid == 0) {
        float s = 0.f;
        #pragma unroll
        for (int i = 0; i < 16; ++i) s += part[i];
        out[0] = s;
    }
}

extern "C" void kernel_launch(void* const* d_in, const int* in_sizes, int n_in,
                              void* d_out, int out_size, void* d_ws, size_t ws_size,
                              hipStream_t stream) {
    const float* user_emb   = (const float*)d_in[0];
    const float* item_emb   = (const float*)d_in[1];
    const int*   batch_user = (const int*)d_in[2];
    const int*   pos_items  = (const int*)d_in[3];
    const int*   top_items  = (const int*)d_in[4];
    const float* mask       = (const float*)d_in[5];
    const int*   is_final   = (const int*)d_in[6];
    float* out = (float*)d_out;

    float* exp_sum  = (float*)d_ws;       // [B_C]
    float* row_loss = exp_sum + B_C;      // [B_C]
    short* item_bf16 = (short*)(row_loss + B_C);
    const size_t need = 2 * B_C * sizeof(float)
                      + (size_t)NGROUPS_PAD * 1024 * sizeof(short);

    hipLaunchKernelGGL(zero_ws_kernel, dim3(1), dim3(B_C), 0, stream, exp_sum);
    if (ws_size >= need) {
        hipLaunchKernelGGL(prep_items_kernel, dim3(NGROUPS_PAD * 128 / 256), dim3(256),
                           0, stream, item_emb, item_bf16);
        hipLaunchKernelGGL(expsum_mfma2_kernel, dim3(ITEM_BLOCKS, B_C / 64), dim3(256),
                           0, stream, user_emb, item_bf16, batch_user, mask, exp_sum);
    } else {
        hipLaunchKernelGGL(expsum_fallback_kernel, dim3(ITEM_BLOCKS, B_C / 64), dim3(256),
                           0, stream, user_emb, item_emb, batch_user, mask, exp_sum);
    }
    hipLaunchKernelGGL(finalize_kernel, dim3(B_C), dim3(64), 0, stream,
                       user_emb, item_emb, batch_user, pos_items, top_items,
                       exp_sum, is_final, row_loss);
    hipLaunchKernelGGL(reduce_kernel, dim3(1), dim3(B_C), 0, stream, row_loss, out);
}